// Round 5
// baseline (426.707 us; speedup 1.0000x reference)
//
#include <hip/hip_runtime.h>
#include <hip/hip_bf16.h>
#include <stdint.h>
#include <type_traits>

#define NHEAD  16
#define DMODEL 1024
#define BATCH  2
#define SEQ    2048
#define DH     64
#define MROWS  (BATCH*SEQ)   // 4096

typedef __attribute__((ext_vector_type(8))) short bf16x8;
typedef __attribute__((ext_vector_type(4))) float f32x4;

__device__ inline short f2bs(float f) {
    __hip_bfloat16 h = __float2bfloat16(f);
    return *reinterpret_cast<short*>(&h);
}

// async global -> LDS, 16B per lane. LDS dest = wave-uniform base + lane*16.
__device__ inline void async16(const void* g, void* l) {
    __builtin_amdgcn_global_load_lds(
        (__attribute__((address_space(1))) void*)g,
        (__attribute__((address_space(3))) void*)l, 16, 0, 0);
}

// ---------------- W fp32 -> bf16 pre-convert (Wq|Wk|Wv packed + Wo) ----------------
// total elems = 4*1024*1024; grid MUST be 4M/(256*8) = 2048 blocks.
__global__ __launch_bounds__(256)
void convert_w(const float* __restrict__ Wq, const float* __restrict__ Wk,
               const float* __restrict__ Wv, const float* __restrict__ Wo,
               __hip_bfloat16* __restrict__ Wqkv, __hip_bfloat16* __restrict__ Wob)
{
    const int idx = (blockIdx.x * 256 + threadIdx.x) * 8;
    if (idx >= 4 * 1048576) return;   // defensive bound
    const float* src;
    __hip_bfloat16* dst;
    if (idx < 3 * 1048576) {
        const int g = idx >> 20;
        src = (g == 0 ? Wq : (g == 1 ? Wk : Wv)) + (idx & 1048575);
        dst = Wqkv + idx;
    } else {
        const int off = idx - 3 * 1048576;
        src = Wo + off;
        dst = Wob + off;
    }
    float4 f0 = *(const float4*)src;
    float4 f1 = *(const float4*)(src + 4);
    short o[8];
    o[0] = f2bs(f0.x); o[1] = f2bs(f0.y); o[2] = f2bs(f0.z); o[3] = f2bs(f0.w);
    o[4] = f2bs(f1.x); o[5] = f2bs(f1.y); o[6] = f2bs(f1.z); o[7] = f2bs(f1.w);
    *(uint4*)dst = *(uint4*)o;
}

// ---------------- V-projection transpose: vp[4096][1024] -> vt[b][h][64][2048] ----------------
__global__ __launch_bounds__(256)
void transpose_v(const __hip_bfloat16* __restrict__ vp, __hip_bfloat16* __restrict__ vt)
{
    __shared__ short L[64 * 72];
    const int t  = threadIdx.x;
    const int st = blockIdx.x & 63;   // 64-row s-tile (2048/64=32 per batch; 64 total)
    const int ht = blockIdx.x >> 6;   // head = 64-col tile
    {
        const int r = t >> 2, cs = (t & 3) * 16;
        const __hip_bfloat16* src = vp + (size_t)(st * 64 + r) * DMODEL + ht * 64 + cs;
        *(uint4*)&L[r * 72 + cs]     = *(const uint4*)src;
        *(uint4*)&L[r * 72 + cs + 8] = *(const uint4*)(src + 8);
    }
    __syncthreads();
    const int d  = t >> 2;            // 0..63 output row (within head)
    const int ss = (t & 3) * 16;      // s chunk
    const int m0 = st * 64;
    const int b  = m0 >> 11;
    const int s0 = (m0 & 2047) + ss;
    short o[16];
#pragma unroll
    for (int i = 0; i < 16; i++) o[i] = L[(ss + i) * 72 + d];
    __hip_bfloat16* dst = vt + ((size_t)((b * NHEAD + ht) * DH + d)) * SEQ + s0;
    *(uint4*)dst       = *(uint4*)&o[0];
    *(uint4*)(dst + 8) = *(uint4*)&o[8];
}

// ---------------- GEMM: C[:,grp] = A_grp[M,K] @ B[N,K]^T + bias ----------------
// B bf16 via global_load_lds w/ chunk swizzle c' = (c + (row>>1))&3 -> 2-way frag reads.
// A: fp32 (reg-convert, padded LDS) or bf16 (async, swizzled). 128x128 tile, BK=32.
template <typename TA, typename TC>
__global__ __launch_bounds__(256, 3)
void gemm_bt(const TA* __restrict__ A0, const TA* __restrict__ A1, const TA* __restrict__ A2,
             const __hip_bfloat16* __restrict__ B,
             const float* __restrict__ b0, const float* __restrict__ b1, const float* __restrict__ b2,
             TC* __restrict__ C0, TC* __restrict__ C1, TC* __restrict__ C2)
{
    constexpr bool AF32 = std::is_same<TA, float>::value;
    constexpr int LDA = AF32 ? 40 : 32;
    __shared__ short As[128 * LDA];
    __shared__ short Bs[128 * 32];

    const int t    = threadIdx.x;
    const int lane = t & 63;
    const int w    = t >> 6;
    const int wm   = (w >> 1) * 64;
    const int wn   = (w & 1) * 64;
    const int quad = lane >> 4;
    const int l16  = lane & 15;

    const int g = blockIdx.x >> 3;
    const TA* A       = (g == 0) ? A0 : (g == 1 ? A1 : A2);
    const float* bias = (g == 0) ? b0 : (g == 1 ? b1 : b2);
    TC* C             = (g == 0) ? C0 : (g == 1 ? C1 : C2);
    const int    bm  = blockIdx.y * 128;
    const int    bnl = (blockIdx.x & 7) * 128;     // col offset within group
    const size_t bng = (size_t)blockIdx.x * 128;   // B row offset (global across groups)
    const int srowA = t >> 1, scolA = (t & 1) * 16;

    f32x4 acc[4][4];
#pragma unroll
    for (int i = 0; i < 4; i++)
#pragma unroll
        for (int j = 0; j < 4; j++)
            acc[i][j] = (f32x4){0.f, 0.f, 0.f, 0.f};

    for (int kt = 0; kt < DMODEL; kt += 32) {
        float fb[16];
        if constexpr (AF32) {
            const float* ap = A + (size_t)(bm + srowA) * DMODEL + kt + scolA;
            *(float4*)&fb[0]  = *(const float4*)(ap + 0);
            *(float4*)&fb[4]  = *(const float4*)(ap + 4);
            *(float4*)&fb[8]  = *(const float4*)(ap + 8);
            *(float4*)&fb[12] = *(const float4*)(ap + 12);
        }
        __syncthreads();   // prev iteration's fragment reads done
        // ---- B tile: async, swizzled ----
#pragma unroll
        for (int i = 0; i < 2; i++) {
            const int s  = i * 256 + t;     // physical 16B segment
            const int br = s >> 2;
            const int c  = ((s & 3) - (br >> 1)) & 3;   // logical chunk for this slot
            async16(B + (bng + br) * DMODEL + kt + c * 8,
                    &Bs[(i * 256 + (w << 6)) * 8]);
        }
        // ---- A tile ----
        if constexpr (AF32) {
            short aT[16];
#pragma unroll
            for (int i = 0; i < 16; i++) aT[i] = f2bs(fb[i]);
            *(uint4*)&As[srowA * LDA + scolA]     = *(uint4*)&aT[0];
            *(uint4*)&As[srowA * LDA + scolA + 8] = *(uint4*)&aT[8];
        } else {
#pragma unroll
            for (int i = 0; i < 2; i++) {
                const int s  = i * 256 + t;
                const int ar = s >> 2;
                const int c  = ((s & 3) - (ar >> 1)) & 3;
                async16((const __hip_bfloat16*)A + (size_t)(bm + ar) * DMODEL + kt + c * 8,
                        &As[(i * 256 + (w << 6)) * 8]);
            }
        }
        __syncthreads();   // drains lgkm + vmcnt (async loads) before frag reads

        bf16x8 af[4], bf[4];
#pragma unroll
        for (int mi = 0; mi < 4; mi++) {
            const int row = wm + mi * 16 + l16;
            if constexpr (AF32) {
                af[mi] = *(const bf16x8*)&As[row * LDA + quad * 8];
            } else {
                const int pc = (quad + (row >> 1)) & 3;
                af[mi] = *(const bf16x8*)&As[row * 32 + pc * 8];
            }
        }
#pragma unroll
        for (int ni = 0; ni < 4; ni++) {
            const int row = wn + ni * 16 + l16;
            const int pc  = (quad + (row >> 1)) & 3;
            bf[ni] = *(const bf16x8*)&Bs[row * 32 + pc * 8];
        }
#pragma unroll
        for (int mi = 0; mi < 4; mi++)
#pragma unroll
            for (int ni = 0; ni < 4; ni++)
                acc[mi][ni] = __builtin_amdgcn_mfma_f32_16x16x32_bf16(
                    af[mi], bf[ni], acc[mi][ni], 0, 0, 0);
    }

#pragma unroll
    for (int mi = 0; mi < 4; mi++) {
#pragma unroll
        for (int ni = 0; ni < 4; ni++) {
            const int row0 = bm + wm + mi * 16 + quad * 4;
            const int coll = bnl + wn + ni * 16 + l16;
            const float bb = bias[coll];
#pragma unroll
            for (int r = 0; r < 4; r++) {
                const float val = acc[mi][ni][r] + bb;
                if constexpr (std::is_same<TC, float>::value)
                    C[(size_t)(row0 + r) * DMODEL + coll] = val;
                else
                    C[(size_t)(row0 + r) * DMODEL + coll] = __float2bfloat16(val);
            }
        }
    }
}

// ---------------- Barrier-free MFMA flash attention ----------------
// Q/K frags: direct per-lane 16B global loads. V frags: direct from pre-transposed vt.
// Only LDS use: wave-local P roundtrip (C-layout -> A-layout). No __syncthreads at all.
#define LPS 68

__global__ __launch_bounds__(256, 4)
void attn_flash(const __hip_bfloat16* __restrict__ qp,
                const __hip_bfloat16* __restrict__ kp,
                const __hip_bfloat16* __restrict__ vt,
                __hip_bfloat16* __restrict__ ao)
{
    __shared__ short Ps[64 * LPS];

    const int t    = threadIdx.x;
    const int lane = t & 63;
    const int w    = t >> 6;
    const int l16  = lane & 15;
    const int quad = lane >> 4;
    const int qt   = (int)gridDim.x - 1 - (int)blockIdx.x;  // heavy tiles first
    const int bh   = blockIdx.y;
    const int b    = bh >> 4;
    const int h    = bh & 15;

    // ---- Q fragments (A-layout): rows 16w+l16, k = quad*8 + [0..7] (+32) ----
    const __hip_bfloat16* qptr =
        qp + (size_t)(b * SEQ + qt * 64 + 16 * w + l16) * DMODEL + h * DH + quad * 8;
    bf16x8 aq0 = *(const bf16x8*)qptr;
    bf16x8 aq1 = *(const bf16x8*)(qptr + 32);

    float m[4], l[4];
    f32x4 oc[4];
#pragma unroll
    for (int r = 0; r < 4; r++) { m[r] = -__builtin_inff(); l[r] = 0.f; }
#pragma unroll
    for (int dt = 0; dt < 4; dt++) oc[dt] = (f32x4){0.f, 0.f, 0.f, 0.f};

    const __hip_bfloat16* kbase = kp + (size_t)(b * SEQ) * DMODEL + h * DH + quad * 8;
    const __hip_bfloat16* vbase = vt + (size_t)(bh * DH) * SEQ;   // [64][2048] for this (b,h)

    for (int jt = 0; jt <= qt; ++jt) {
        // ---- S = Q K^T : B-frag = K[row 16ct+l16][k quad*8..] direct from global ----
        f32x4 sc[4];
#pragma unroll
        for (int ct = 0; ct < 4; ct++) {
            const __hip_bfloat16* kptr = kbase + (size_t)(jt * 64 + 16 * ct + l16) * DMODEL;
            bf16x8 bk0 = *(const bf16x8*)kptr;
            bf16x8 bk1 = *(const bf16x8*)(kptr + 32);
            sc[ct] = __builtin_amdgcn_mfma_f32_16x16x32_bf16(
                aq0, bk0, (f32x4){0.f, 0.f, 0.f, 0.f}, 0, 0, 0);
            sc[ct] = __builtin_amdgcn_mfma_f32_16x16x32_bf16(aq1, bk1, sc[ct], 0, 0, 0);
        }

        // ---- scale + causal mask (C layout: row = 16w+quad*4+r, col = 16ct+l16) ----
        float p[4][4];
        const bool diag = (jt == qt);
#pragma unroll
        for (int ct = 0; ct < 4; ct++) {
#pragma unroll
            for (int r = 0; r < 4; r++) {
                float v = sc[ct][r] * 0.03125f;
                if (diag && (16 * ct + l16 > 16 * w + quad * 4 + r)) v = -__builtin_inff();
                p[ct][r] = v;
            }
        }

        // ---- online softmax (row spread across the 16 lanes of a quad) ----
        float alpha[4];
#pragma unroll
        for (int r = 0; r < 4; r++) {
            float mx = fmaxf(fmaxf(p[0][r], p[1][r]), fmaxf(p[2][r], p[3][r]));
#pragma unroll
            for (int d = 1; d < 16; d <<= 1) mx = fmaxf(mx, __shfl_xor(mx, d));
            const float mn = fmaxf(m[r], mx);
            alpha[r] = __expf(m[r] - mn);
            float sum = 0.f;
#pragma unroll
            for (int ct = 0; ct < 4; ct++) {
                p[ct][r] = __expf(p[ct][r] - mn);
                sum += p[ct][r];
            }
#pragma unroll
            for (int d = 1; d < 16; d <<= 1) sum += __shfl_xor(sum, d);
            l[r] = alpha[r] * l[r] + sum;
            m[r] = mn;
        }

        // ---- P: C-layout -> A-layout via wave-local LDS roundtrip ----
#pragma unroll
        for (int ct = 0; ct < 4; ct++)
#pragma unroll
            for (int r = 0; r < 4; r++)
                Ps[(16 * w + quad * 4 + r) * LPS + 16 * ct + l16] = f2bs(p[ct][r]);
        bf16x8 ap0 = *(const bf16x8*)&Ps[(16 * w + l16) * LPS + quad * 8];
        bf16x8 ap1 = *(const bf16x8*)&Ps[(16 * w + l16) * LPS + quad * 8 + 32];

        // ---- O = alpha*O + P V : B-frag = vt[d=16dt+l16][key jt*64+quad*8..] ----
#pragma unroll
        for (int dt = 0; dt < 4; dt++)
#pragma unroll
            for (int r = 0; r < 4; r++) oc[dt][r] *= alpha[r];
#pragma unroll
        for (int dt = 0; dt < 4; dt++) {
            const __hip_bfloat16* vptr = vbase + (size_t)(16 * dt + l16) * SEQ + jt * 64 + quad * 8;
            bf16x8 bv0 = *(const bf16x8*)vptr;
            bf16x8 bv1 = *(const bf16x8*)(vptr + 32);
            oc[dt] = __builtin_amdgcn_mfma_f32_16x16x32_bf16(ap0, bv0, oc[dt], 0, 0, 0);
            oc[dt] = __builtin_amdgcn_mfma_f32_16x16x32_bf16(ap1, bv1, oc[dt], 0, 0, 0);
        }
    }

    // ---- normalize + write (C layout) ----
#pragma unroll
    for (int r = 0; r < 4; r++) {
        const float inv = 1.f / l[r];
        const size_t base =
            (size_t)(b * SEQ + qt * 64 + 16 * w + quad * 4 + r) * DMODEL + h * DH;
#pragma unroll
        for (int dt = 0; dt < 4; dt++)
            ao[base + 16 * dt + l16] = __float2bfloat16(oc[dt][r] * inv);
    }
}

// ---------------- launch ----------------
extern "C" void kernel_launch(void* const* d_in, const int* in_sizes, int n_in,
                              void* d_out, int out_size, void* d_ws, size_t ws_size,
                              hipStream_t stream) {
    const float* q  = (const float*)d_in[0];
    const float* k  = (const float*)d_in[1];
    const float* v  = (const float*)d_in[2];
    const float* Wq = (const float*)d_in[3];
    const float* bq = (const float*)d_in[4];
    const float* Wk = (const float*)d_in[5];
    const float* bk = (const float*)d_in[6];
    const float* Wv = (const float*)d_in[7];
    const float* bv = (const float*)d_in[8];
    const float* Wo = (const float*)d_in[9];
    const float* bo = (const float*)d_in[10];
    float* out = (float*)d_out;

    // ws layout (bf16 elems): Wqkv 3M | Wob 1M | qp 4M | kp 4M | vp 4M | vt 4M  = 40 MB
    __hip_bfloat16* Wqkv = (__hip_bfloat16*)d_ws;
    __hip_bfloat16* Wob  = Wqkv + (size_t)3072 * 1024;
    __hip_bfloat16* qp   = Wob  + (size_t)1024 * 1024;
    __hip_bfloat16* kp   = qp   + (size_t)MROWS * DMODEL;
    __hip_bfloat16* vp   = kp   + (size_t)MROWS * DMODEL;
    __hip_bfloat16* vtg  = vp   + (size_t)MROWS * DMODEL;
    __hip_bfloat16* ao   = vp;   // reuse: vp dead after transpose_v

    // 4M elems / (256 thr * 8 elems) = 2048 blocks (R4 bug: 2560 -> OOB read past Wo)
    hipLaunchKernelGGL(convert_w, dim3(2048), dim3(256), 0, stream,
                       Wq, Wk, Wv, Wo, Wqkv, Wob);

    // fused QKV projection: one dispatch, 24 N-blocks x 32 M-blocks
    hipLaunchKernelGGL((gemm_bt<float, __hip_bfloat16>), dim3(24, 32), dim3(256), 0, stream,
                       q, k, v, Wqkv, bq, bk, bv, qp, kp, vp);

    hipLaunchKernelGGL(transpose_v, dim3(1024), dim3(256), 0, stream, vp, vtg);

    hipLaunchKernelGGL(attn_flash, dim3(SEQ / 64, BATCH * NHEAD), dim3(256), 0, stream,
                       qp, kp, vtg, ao);

    hipLaunchKernelGGL((gemm_bt<__hip_bfloat16, float>), dim3(8, 32), dim3(256), 0, stream,
                       ao, ao, ao, Wob, bo, bo, bo, out, out, out);
}